// Round 4
// baseline (208.174 us; speedup 1.0000x reference)
//
#include <hip/hip_runtime.h>

#define NPTS 8192
#define DIM  128
#define NCLS 64
#define NT   64          // 128-row tiles
#define FEPS 1e-16f

// ws layout (float elements)
#define WS_S     0          // 8192 floats: S_i
#define WS_SQ    8192       // 8192 floats
#define WS_CNT   16384      // 64 ints
#define WS_OFFS  16448      // 65 ints
#define WS_POFF  16520      // 65 ints (prefix of cnt^2)
#define WS_CUR   16592      // 64 ints
#define WS_MEM   16656      // 8192 ints
#define WS_RANK  24848      // 8192 ints
#define WS_LOSS  33040      // 1 float
#define WS_G     33044      // 16B aligned (33044*4 = 8261*16): 2MB bf16 swizzled features
#define WS_DP    557332     // ~1.1M floats: per-pair distances

typedef float f32x4 __attribute__((ext_vector_type(4)));
typedef short bf16x8 __attribute__((ext_vector_type(8)));

__device__ inline unsigned short f2bf(float x) {
    unsigned u = __float_as_uint(x);
    u += 0x7fffu + ((u >> 16) & 1u);   // RNE
    return (unsigned short)(u >> 16);
}

// ---- prep: squared norms + bf16 swizzled features + class counts ----
// G layout (u16 units): tile t=i>>7 (16384 each) | chunk c=k>>3 (1024 each)
//                       | m=i&127 (8 each) | k&7
__global__ void prep_kernel(const float* __restrict__ feat,
                            const int* __restrict__ labels,
                            float* __restrict__ sq,
                            unsigned short* __restrict__ G,
                            int* __restrict__ cnt) {
    int w = threadIdx.x >> 6, lane = threadIdx.x & 63;
    int i = blockIdx.x * 4 + w;
    const float2* row = (const float2*)(feat + (size_t)i * DIM);
    float2 v = row[lane];
    unsigned pack = ((unsigned)f2bf(v.y) << 16) | (unsigned)f2bf(v.x);
    int t = i >> 7, m = i & 127;
    int c = lane >> 2;
    int pos = (lane & 3) * 2;
    *(unsigned*)(&G[(size_t)t * 16384 + c * 1024 + m * 8 + pos]) = pack;
    float s = v.x * v.x + v.y * v.y;
#pragma unroll
    for (int off = 32; off > 0; off >>= 1) s += __shfl_down(s, off, 64);
    if (lane == 0) {
        sq[i] = s;
        atomicAdd(&cnt[labels[i]], 1);
    }
}

// ---- offsets via wave scan (64 threads) ----
__global__ void offsets_kernel(const int* __restrict__ cnt,
                               int* __restrict__ offs, int* __restrict__ poff) {
    int c = threadIdx.x;
    int v = cnt[c], v2 = v * v;
    int s1 = v, s2 = v2;
#pragma unroll
    for (int o = 1; o < 64; o <<= 1) {
        int t1 = __shfl_up(s1, o, 64);
        int t2 = __shfl_up(s2, o, 64);
        if (c >= o) { s1 += t1; s2 += t2; }
    }
    offs[c] = s1 - v; poff[c] = s2 - v2;
    if (c == 63) { offs[64] = s1; poff[64] = s2; }
}

__global__ void scatter_kernel(const int* __restrict__ labels,
                               const int* __restrict__ offs,
                               int* __restrict__ cur, int* __restrict__ mem,
                               int* __restrict__ rank) {
    int n = blockIdx.x * 256 + threadIdx.x;
    int c = labels[n];
    int pos = atomicAdd(&cur[c], 1);
    mem[offs[c] + pos] = n;
    rank[n] = pos;
}

// ---- main N^2 pass, LDS-free fragments, triangular grid ----
// S_i += sum exp(1-d) over label-differs; same-label distances scattered to dpair.
__launch_bounds__(256, 3)
__global__ void gemm_S(const uint4* __restrict__ G,
                       const float* __restrict__ sq,
                       const int* __restrict__ labels,
                       const int* __restrict__ rank,
                       const int* __restrict__ cnt,
                       const int* __restrict__ poff,
                       float* __restrict__ S,
                       float* __restrict__ dpair) {
    // decode linear block index -> upper-triangular (bt, jt)
    int p = blockIdx.x;
    float disc = 64.5f * 64.5f - 2.0f * (float)p;
    int bt = (int)(64.5f - sqrtf(disc));
    if (bt < 0) bt = 0; if (bt > 63) bt = 63;
    while (bt > 0 && (bt * NT - (bt * (bt - 1)) / 2) > p) --bt;
    while (((bt + 1) * NT - ((bt + 1) * bt) / 2) <= p) ++bt;
    int jt = bt + (p - (bt * NT - (bt * (bt - 1)) / 2));

    __shared__ float sqi[128], sqj[128];
    __shared__ int lli[128], llj[128], rki[128], rkj[128];
    __shared__ int s_cnt[NCLS], s_poff[NCLS];

    const int tid = threadIdx.x;
    const int w = tid >> 6, lane = tid & 63;
    const int wr = w >> 1, wc = w & 1;
    const int q = lane >> 4, ml = lane & 15;
    const int ib = bt * 128, jb = jt * 128;
    const bool diag = (bt == jt);

    if (tid < 128) {
        int i = ib + tid;
        sqi[tid] = sq[i]; lli[tid] = labels[i]; rki[tid] = rank[i];
    } else {
        int j = jb + tid - 128;
        sqj[tid - 128] = sq[j]; llj[tid - 128] = labels[j]; rkj[tid - 128] = rank[j];
    }
    if (tid < NCLS) { s_cnt[tid] = cnt[tid]; s_poff[tid] = poff[tid]; }
    __syncthreads();

    const bf16x8* A8 = (const bf16x8*)(G + (size_t)bt * 2048);
    const bf16x8* B8 = (const bf16x8*)(G + (size_t)jt * 2048);

    f32x4 acc[4][4];
#pragma unroll
    for (int a = 0; a < 4; ++a)
#pragma unroll
        for (int b = 0; b < 4; ++b) acc[a][b] = (f32x4){0.f, 0.f, 0.f, 0.f};

#pragma unroll
    for (int s = 0; s < 4; ++s) {
        bf16x8 af[4], bf[4];
        int kbase = (s * 4 + q) * 128;
#pragma unroll
        for (int ii = 0; ii < 4; ++ii) af[ii] = A8[kbase + wr * 64 + ii * 16 + ml];
#pragma unroll
        for (int jj = 0; jj < 4; ++jj) bf[jj] = B8[kbase + wc * 64 + jj * 16 + ml];
#pragma unroll
        for (int ii = 0; ii < 4; ++ii)
#pragma unroll
            for (int jj = 0; jj < 4; ++jj)
                acc[ii][jj] = __builtin_amdgcn_mfma_f32_16x16x32_bf16(af[ii], bf[jj], acc[ii][jj], 0, 0, 0);
    }

    // epilogue
    int cl[4], lcj[4], rbj[4]; float sj[4];
#pragma unroll
    for (int jj = 0; jj < 4; ++jj) {
        cl[jj] = wc * 64 + jj * 16 + ml;
        lcj[jj] = llj[cl[jj]]; sj[jj] = sqj[cl[jj]]; rbj[jj] = rkj[cl[jj]];
    }
    float colsum[4] = {0.f, 0.f, 0.f, 0.f};

#pragma unroll
    for (int ii = 0; ii < 4; ++ii) {
        int rl = wr * 64 + ii * 16 + q * 4;
        int lri[4], rai[4]; float si4[4];
#pragma unroll
        for (int r = 0; r < 4; ++r) {
            lri[r] = lli[rl + r]; si4[r] = sqi[rl + r]; rai[r] = rki[rl + r];
        }
        float rs[4] = {0.f, 0.f, 0.f, 0.f};
#pragma unroll
        for (int jj = 0; jj < 4; ++jj)
#pragma unroll
            for (int r = 0; r < 4; ++r) {
                float d2 = fmaf(-2.0f, acc[ii][jj][r], si4[r] + sj[jj]);
                float d = sqrtf(fmaxf(d2, FEPS));
                float e = __expf(1.0f - d);
                bool same = (lri[r] == lcj[jj]);
                float ep = same ? 0.0f : e;
                rs[r] += ep;
                colsum[jj] += ep;
                if (same) {
                    int i = ib + rl + r, j = jb + cl[jj];
                    if (i != j) {
                        int c = lri[r];
                        int n = s_cnt[c], base = s_poff[c];
                        dpair[base + rai[r] * n + rbj[jj]] = d;
                        if (!diag) dpair[base + rbj[jj] * n + rai[r]] = d;
                    }
                }
            }
        // row reduce across ml (16 lanes)
#pragma unroll
        for (int m = 1; m < 16; m <<= 1)
#pragma unroll
            for (int r = 0; r < 4; ++r) rs[r] += __shfl_xor(rs[r], m, 64);
        if (ml == 0) {
#pragma unroll
            for (int r = 0; r < 4; ++r) atomicAdd(&S[ib + rl + r], rs[r]);
        }
    }
    // col reduce across q
    if (!diag) {
#pragma unroll
        for (int m = 16; m < 64; m <<= 1)
#pragma unroll
            for (int jj = 0; jj < 4; ++jj) colsum[jj] += __shfl_xor(colsum[jj], m, 64);
        if (q == 0) {
#pragma unroll
            for (int jj = 0; jj < 4; ++jj)
                atomicAdd(&S[jb + cl[jj]], colsum[jj]);
        }
    }
}

// ---- per-pair loss over positive pairs ----
__global__ void pairB_kernel(const float* __restrict__ S,
                             const int* __restrict__ cnt, const int* __restrict__ offs,
                             const int* __restrict__ poff, const int* __restrict__ mem,
                             const float* __restrict__ dpair,
                             float* __restrict__ loss_sum) {
    int total = poff[NCLS];
    int stride = gridDim.x * blockDim.x;
    float lsum = 0.f;
    for (int p = blockIdx.x * blockDim.x + threadIdx.x; p < total; p += stride) {
        int lo = 0, hi = NCLS - 1;
        while (lo < hi) {
            int mid = (lo + hi + 1) >> 1;
            if (p >= poff[mid]) lo = mid; else hi = mid - 1;
        }
        int c = lo;
        unsigned pl = (unsigned)(p - poff[c]);
        unsigned n = (unsigned)cnt[c];
        int a = (int)(pl / n);
        int b = (int)(pl - (unsigned)a * n);
        int ia = mem[offs[c] + a], jb_ = mem[offs[c] + b];
        float d = (a == b) ? 1e-8f : dpair[p];
        float J = __logf(S[ia] + S[jb_]) + d;
        float h = fmaxf(J, 0.0f);
        lsum += h * h;
    }
#pragma unroll
    for (int off = 32; off > 0; off >>= 1) lsum += __shfl_down(lsum, off, 64);
    if ((threadIdx.x & 63) == 0) atomicAdd(loss_sum, lsum);
}

__global__ void finalize_kernel(const float* __restrict__ loss_sum,
                                const int* __restrict__ poff,
                                float* __restrict__ out) {
    out[0] = loss_sum[0] / (2.0f * (float)poff[NCLS]);
}

extern "C" void kernel_launch(void* const* d_in, const int* in_sizes, int n_in,
                              void* d_out, int out_size, void* d_ws, size_t ws_size,
                              hipStream_t stream) {
    const float* feat = (const float*)d_in[0];
    const int* labels = (const int*)d_in[1];

    float* ws = (float*)d_ws;
    float* S = ws + WS_S;
    float* sq = ws + WS_SQ;
    int* cnt = (int*)(ws + WS_CNT);
    int* offs = (int*)(ws + WS_OFFS);
    int* poff = (int*)(ws + WS_POFF);
    int* cur = (int*)(ws + WS_CUR);
    int* mem = (int*)(ws + WS_MEM);
    int* rank = (int*)(ws + WS_RANK);
    float* loss_sum = ws + WS_LOSS;
    unsigned short* G16 = (unsigned short*)(ws + WS_G);
    const uint4* G4 = (const uint4*)(ws + WS_G);
    float* dpair = ws + WS_DP;

    // zero S, cnt, cur, loss (rest fully overwritten)
    hipMemsetAsync(d_ws, 0, (WS_LOSS + 1) * sizeof(float), stream);

    prep_kernel<<<NPTS / 4, 256, 0, stream>>>(feat, labels, sq, G16, cnt);
    offsets_kernel<<<1, 64, 0, stream>>>(cnt, offs, poff);
    scatter_kernel<<<NPTS / 256, 256, 0, stream>>>(labels, offs, cur, mem, rank);

    gemm_S<<<NT * (NT + 1) / 2, 256, 0, stream>>>(G4, sq, labels, rank, cnt, poff, S, dpair);

    pairB_kernel<<<512, 256, 0, stream>>>(S, cnt, offs, poff, mem, dpair, loss_sum);

    finalize_kernel<<<1, 1, 0, stream>>>(loss_sum, poff, (float*)d_out);
}